// Round 4
// baseline (1420.461 us; speedup 1.0000x reference)
//
#include <hip/hip_runtime.h>
#include <hip/hip_bf16.h>
#include <cmath>

#define BQ 2
#define SQ 2048
#define DM 512
#define DI 1024
#define DSTATE 16
#define DCONV 4
#define DTR 32
#define NLAYERS 2

typedef __attribute__((ext_vector_type(8))) short bf16x8;
typedef __attribute__((ext_vector_type(4))) float f32x4;

__device__ __forceinline__ unsigned short f2bf(float f) {
    __hip_bfloat16 h = __float2bfloat16(f);
    return *reinterpret_cast<unsigned short*>(&h);
}

// ---------------------------------------------------------------- transpose
// input_data (B, DM, SQ) -> x (B, SQ, DM)
__global__ __launch_bounds__(256) void k_transpose(const float* __restrict__ in,
                                                   float* __restrict__ out) {
    __shared__ float tile[32][33];
    int b = blockIdx.z;
    int s0 = blockIdx.x * 32, c0 = blockIdx.y * 32;
    int tx = threadIdx.x, ty = threadIdx.y;  // block (32,8)
#pragma unroll
    for (int i = 0; i < 4; i++)
        tile[ty + i * 8][tx] = in[((size_t)b * DM + c0 + ty + i * 8) * SQ + s0 + tx];
    __syncthreads();
#pragma unroll
    for (int i = 0; i < 4; i++)
        out[((size_t)b * SQ + s0 + ty + i * 8) * DM + c0 + tx] = tile[tx][ty + i * 8];
}

// ---------------------------------------------------------------- fp32 -> bf16 convert (n4 = n/4)
__global__ __launch_bounds__(256) void k_cvt(const float* __restrict__ in,
                                             unsigned short* __restrict__ out, int n4) {
    int i = blockIdx.x * 256 + threadIdx.x;
    if (i >= n4) return;
    float4 v = ((const float4*)in)[i];
    ushort4 o;
    o.x = f2bf(v.x); o.y = f2bf(v.y); o.z = f2bf(v.z); o.w = f2bf(v.w);
    ((ushort4*)out)[i] = o;
}

// ---------------------------------------------------------------- rmsnorm (D=512), bf16 output
__global__ __launch_bounds__(256) void k_rmsnorm_bf(const float* __restrict__ x,
                                                    const float* __restrict__ w,
                                                    unsigned short* __restrict__ out) {
    int row = blockIdx.x;
    const float* xr = x + (size_t)row * DM;
    float v0 = xr[threadIdx.x];
    float v1 = xr[threadIdx.x + 256];
    float ss = v0 * v0 + v1 * v1;
#pragma unroll
    for (int off = 32; off >= 1; off >>= 1) ss += __shfl_xor(ss, off);
    __shared__ float wc[4];
    if ((threadIdx.x & 63) == 0) wc[threadIdx.x >> 6] = ss;
    __syncthreads();
    ss = wc[0] + wc[1] + wc[2] + wc[3];
    float r = rsqrtf(ss * (1.0f / DM) + 1e-5f);
    out[(size_t)row * DM + threadIdx.x] = f2bf(v0 * r * w[threadIdx.x]);
    out[(size_t)row * DM + threadIdx.x + 256] = f2bf(v1 * r * w[threadIdx.x + 256]);
}

// ---------------------------------------------------------------- rmsnorm fp32 output (final)
__global__ __launch_bounds__(256) void k_rmsnorm_f32(const float* __restrict__ x,
                                                     const float* __restrict__ w,
                                                     float* __restrict__ out) {
    int row = blockIdx.x;
    const float* xr = x + (size_t)row * DM;
    float v0 = xr[threadIdx.x];
    float v1 = xr[threadIdx.x + 256];
    float ss = v0 * v0 + v1 * v1;
#pragma unroll
    for (int off = 32; off >= 1; off >>= 1) ss += __shfl_xor(ss, off);
    __shared__ float wc[4];
    if ((threadIdx.x & 63) == 0) wc[threadIdx.x >> 6] = ss;
    __syncthreads();
    ss = wc[0] + wc[1] + wc[2] + wc[3];
    float r = rsqrtf(ss * (1.0f / DM) + 1e-5f);
    out[(size_t)row * DM + threadIdx.x] = v0 * r * w[threadIdx.x];
    out[(size_t)row * DM + threadIdx.x + 256] = v1 * r * w[threadIdx.x + 256];
}

// ---------------------------------------------------------------- bf16 MFMA GEMM  C = A @ W^T (+resid)
// A (M,K) bf16 lda, W (N,K) bf16 ldw, C (M,N) fp32 ldc. 128x128 tile, BK=32.
// Slot swizzle: within each row's four 16B k-slices, slot s holds global slice s^(row&3);
// applied to global SOURCE (staging) and LDS READ (same involution) — LDS dest stays linear.
__global__ __launch_bounds__(256) void k_gemm_bf16(const unsigned short* __restrict__ A, int lda,
                                                   const unsigned short* __restrict__ W, int ldw,
                                                   float* __restrict__ C, int ldc, int K,
                                                   const float* __restrict__ resid, int ldr) {
    __shared__ __align__(16) unsigned short As[128 * 32];
    __shared__ __align__(16) unsigned short Bs[128 * 32];
    const int bm = blockIdx.y * 128, bn = blockIdx.x * 128;
    const int tid = threadIdx.x;
    const int w = tid >> 6, l = tid & 63;
    const int wr = w >> 1, wc = w & 1;
    const int lg = l >> 4, lr16 = l & 15;
    f32x4 acc[4][4] = {};
    for (int k0 = 0; k0 < K; k0 += 32) {
        __syncthreads();
#pragma unroll
        for (int i = 0; i < 2; i++) {
            int slot = i * 256 + tid;
            int row = slot >> 2, s = slot & 3;
            int sg = s ^ (row & 3);
            __builtin_amdgcn_global_load_lds(
                (const __attribute__((address_space(1))) unsigned int*)(A + (size_t)(bm + row) * lda + k0 + sg * 8),
                (__attribute__((address_space(3))) unsigned int*)(As + slot * 8), 16, 0, 0);
            __builtin_amdgcn_global_load_lds(
                (const __attribute__((address_space(1))) unsigned int*)(W + (size_t)(bn + row) * ldw + k0 + sg * 8),
                (__attribute__((address_space(3))) unsigned int*)(Bs + slot * 8), 16, 0, 0);
        }
        asm volatile("s_waitcnt vmcnt(0)" ::: "memory");
        __syncthreads();
        bf16x8 fa[4], fb[4];
#pragma unroll
        for (int f = 0; f < 4; f++) {
            int ar = wr * 64 + f * 16 + lr16;
            fa[f] = *(const bf16x8*)&As[ar * 32 + (lg ^ (ar & 3)) * 8];
            int br = wc * 64 + f * 16 + lr16;
            fb[f] = *(const bf16x8*)&Bs[br * 32 + (lg ^ (br & 3)) * 8];
        }
#pragma unroll
        for (int fi = 0; fi < 4; fi++)
#pragma unroll
            for (int fj = 0; fj < 4; fj++)
                acc[fi][fj] = __builtin_amdgcn_mfma_f32_16x16x32_bf16(fa[fi], fb[fj], acc[fi][fj], 0, 0, 0);
    }
#pragma unroll
    for (int fi = 0; fi < 4; fi++)
#pragma unroll
        for (int fj = 0; fj < 4; fj++)
#pragma unroll
            for (int r = 0; r < 4; r++) {
                int m = bm + wr * 64 + fi * 16 + lg * 4 + r;
                int n = bn + wc * 64 + fj * 16 + lr16;
                float v = acc[fi][fj][r];
                if (resid) v += resid[(size_t)m * ldr + n];
                C[(size_t)m * ldc + n] = v;
            }
}

// ---------------------------------------------------------------- bf16 MFMA GEMM, N=64 (x_proj)
// 128-row M tile x 64 N; 4 waves stacked on M (32 rows each).
__global__ __launch_bounds__(256) void k_gemm_bf16_n64(const unsigned short* __restrict__ A, int lda,
                                                       const unsigned short* __restrict__ W, int ldw,
                                                       float* __restrict__ C, int ldc, int K) {
    __shared__ __align__(16) unsigned short As[128 * 32];
    __shared__ __align__(16) unsigned short Bs[64 * 32];
    const int bm = blockIdx.x * 128;
    const int tid = threadIdx.x;
    const int w = tid >> 6, l = tid & 63;
    const int lg = l >> 4, lr16 = l & 15;
    f32x4 acc[2][4] = {};
    for (int k0 = 0; k0 < K; k0 += 32) {
        __syncthreads();
#pragma unroll
        for (int i = 0; i < 2; i++) {
            int slot = i * 256 + tid;
            int row = slot >> 2, s = slot & 3;
            int sg = s ^ (row & 3);
            __builtin_amdgcn_global_load_lds(
                (const __attribute__((address_space(1))) unsigned int*)(A + (size_t)(bm + row) * lda + k0 + sg * 8),
                (__attribute__((address_space(3))) unsigned int*)(As + slot * 8), 16, 0, 0);
        }
        {
            int slot = tid;
            int row = slot >> 2, s = slot & 3;
            int sg = s ^ (row & 3);
            __builtin_amdgcn_global_load_lds(
                (const __attribute__((address_space(1))) unsigned int*)(W + (size_t)row * ldw + k0 + sg * 8),
                (__attribute__((address_space(3))) unsigned int*)(Bs + slot * 8), 16, 0, 0);
        }
        asm volatile("s_waitcnt vmcnt(0)" ::: "memory");
        __syncthreads();
        bf16x8 fa[2], fb[4];
#pragma unroll
        for (int f = 0; f < 2; f++) {
            int ar = w * 32 + f * 16 + lr16;
            fa[f] = *(const bf16x8*)&As[ar * 32 + (lg ^ (ar & 3)) * 8];
        }
#pragma unroll
        for (int f = 0; f < 4; f++) {
            int br = f * 16 + lr16;
            fb[f] = *(const bf16x8*)&Bs[br * 32 + (lg ^ (br & 3)) * 8];
        }
#pragma unroll
        for (int fi = 0; fi < 2; fi++)
#pragma unroll
            for (int fj = 0; fj < 4; fj++)
                acc[fi][fj] = __builtin_amdgcn_mfma_f32_16x16x32_bf16(fa[fi], fb[fj], acc[fi][fj], 0, 0, 0);
    }
#pragma unroll
    for (int fi = 0; fi < 2; fi++)
#pragma unroll
        for (int fj = 0; fj < 4; fj++)
#pragma unroll
            for (int r = 0; r < 4; r++) {
                int m = bm + w * 32 + fi * 16 + lg * 4 + r;
                int n = fj * 16 + lr16;
                C[(size_t)m * ldc + n] = acc[fi][fj][r];
            }
}

// ---------------------------------------------------------------- fp32 GEMM (small: dt projection)
__global__ __launch_bounds__(256) void k_gemm(const float* __restrict__ A, int lda,
                                              const float* __restrict__ W, int ldw,
                                              float* __restrict__ C, int ldc, int K,
                                              const float* __restrict__ bias, int act,
                                              const float* __restrict__ resid, int ldr) {
    __shared__ float As[16][64];
    __shared__ float Bs[16][64];
    int bm = blockIdx.y * 64, bn = blockIdx.x * 64;
    int tid = threadIdx.x;
    int tx = tid & 15, ty = tid >> 4;
    int lr = tid >> 2, lk = (tid & 3) << 2;
    float acc[4][4] = {};
    for (int k0 = 0; k0 < K; k0 += 16) {
        float4 av = *(const float4*)&A[(size_t)(bm + lr) * lda + k0 + lk];
        float4 wv = *(const float4*)&W[(size_t)(bn + lr) * ldw + k0 + lk];
        __syncthreads();
        As[lk + 0][lr] = av.x; As[lk + 1][lr] = av.y;
        As[lk + 2][lr] = av.z; As[lk + 3][lr] = av.w;
        Bs[lk + 0][lr] = wv.x; Bs[lk + 1][lr] = wv.y;
        Bs[lk + 2][lr] = wv.z; Bs[lk + 3][lr] = wv.w;
        __syncthreads();
#pragma unroll
        for (int k = 0; k < 16; k++) {
            float a[4], bb[4];
#pragma unroll
            for (int i = 0; i < 4; i++) a[i] = As[k][ty * 4 + i];
#pragma unroll
            for (int j = 0; j < 4; j++) bb[j] = Bs[k][tx * 4 + j];
#pragma unroll
            for (int i = 0; i < 4; i++)
#pragma unroll
                for (int j = 0; j < 4; j++) acc[i][j] += a[i] * bb[j];
        }
    }
#pragma unroll
    for (int i = 0; i < 4; i++) {
        int m = bm + ty * 4 + i;
#pragma unroll
        for (int j = 0; j < 4; j++) {
            int n = bn + tx * 4 + j;
            float v = acc[i][j];
            if (bias) v += bias[n];
            if (act == 1) v = fmaxf(v, 0.f) + log1pf(expf(-fabsf(v)));
            if (resid) v += resid[(size_t)m * ldr + n];
            C[(size_t)m * ldc + n] = v;
        }
    }
}

// ---------------------------------------------------------------- causal depthwise conv (k=4) + silu
// writes fp32 u (for scan) and bf16 u (for x_proj MFMA)
__global__ __launch_bounds__(256) void k_conv_silu(const float* __restrict__ xz,
                                                   const float* __restrict__ cw,
                                                   const float* __restrict__ cb,
                                                   float* __restrict__ u,
                                                   unsigned short* __restrict__ ubf) {
    int bt = blockIdx.x;       // b*SQ + t
    int t = bt & (SQ - 1);
#pragma unroll
    for (int dd = 0; dd < 4; dd++) {
        int d = dd * 256 + threadIdx.x;
        float acc = cb[d];
#pragma unroll
        for (int k = 0; k < DCONV; k++) {
            int tk = t + k - (DCONV - 1);
            if (tk >= 0)
                acc += xz[((size_t)(bt + k - (DCONV - 1))) * (2 * DI) + d] * cw[d * DCONV + k];
        }
        float sig = 1.f / (1.f + expf(-acc));
        float v = acc * sig;
        u[(size_t)bt * DI + d] = v;
        ubf[(size_t)bt * DI + d] = f2bf(v);
    }
}

// ---------------------------------------------------------------- state-parallel selective scan
// thread = (s, d_local): 256 = 16 states x 16 channels; grid = BQ * DI/16 = 128
// output: y_gated in bf16 (consumed by out_proj MFMA)
__global__ __launch_bounds__(256) void k_scan2(const float* __restrict__ xdbl,
                                               const float* __restrict__ dt,
                                               const float* __restrict__ u,
                                               const float* __restrict__ xz,
                                               const float* __restrict__ A_log,
                                               const float* __restrict__ Dp,
                                               unsigned short* __restrict__ yout) {
    int b = blockIdx.x >> 6;
    int d0 = (blockIdx.x & 63) << 4;
    int tid = threadIdx.x;
    int s = tid & 15, dl = tid >> 4;
    int d = d0 + dl;
    float a = -expf(A_log[(size_t)d * DSTATE + s]);
    float h = 0.f;
    float Dv = Dp[d];
    __shared__ float sdt[64][16], su[64][16], sz[64][16], sB[64][16], sC[64][16];
    for (int t0 = 0; t0 < SQ; t0 += 64) {
        __syncthreads();
#pragma unroll
        for (int i = 0; i < 4; i++) {
            int e = i * 256 + tid;          // 0..1023
            int tt = e >> 4, j = e & 15;
            size_t rowm = (size_t)(b * SQ + t0 + tt);
            sdt[tt][j] = dt[rowm * DI + d0 + j];
            su[tt][j]  = u[rowm * DI + d0 + j];
            sz[tt][j]  = xz[rowm * (2 * DI) + DI + d0 + j];
            sB[tt][j]  = xdbl[rowm * 64 + DTR + j];
            sC[tt][j]  = xdbl[rowm * 64 + DTR + DSTATE + j];
        }
        __syncthreads();
        for (int tt = 0; tt < 64; tt++) {
            float dtv = sdt[tt][dl];
            float uv  = su[tt][dl];
            float dA = __expf(dtv * a);
            h = dA * h + dtv * uv * sB[tt][s];
            float y = h * sC[tt][s];
            y += __shfl_xor(y, 1);
            y += __shfl_xor(y, 2);
            y += __shfl_xor(y, 4);
            y += __shfl_xor(y, 8);
            if (s == 0) {
                y += uv * Dv;
                float zv = sz[tt][dl];
                float g = zv / (1.f + __expf(-zv));
                yout[(size_t)(b * SQ + t0 + tt) * DI + d] = f2bf(y * g);
            }
        }
    }
}

// ---------------------------------------------------------------- emb gather (mask is int32)
__global__ __launch_bounds__(256) void k_emb(const float* __restrict__ tokens,
                                             const int* __restrict__ mask,
                                             float* __restrict__ emb) {
    int b = blockIdx.x;
    int cnt = 0;
    for (int i = threadIdx.x; i < SQ; i += 256) cnt += mask[b * SQ + i] ? 1 : 0;
#pragma unroll
    for (int off = 32; off >= 1; off >>= 1) cnt += __shfl_xor(cnt, off);
    __shared__ int wc[4];
    if ((threadIdx.x & 63) == 0) wc[threadIdx.x >> 6] = cnt;
    __syncthreads();
    int total = wc[0] + wc[1] + wc[2] + wc[3];
    int idx = total > 0 ? total - 1 : 0;
    for (int i = threadIdx.x; i < DM; i += 256)
        emb[b * DM + i] = tokens[((size_t)b * SQ + idx) * DM + i];
}

// ---------------------------------------------------------------- host
extern "C" void kernel_launch(void* const* d_in, const int* in_sizes, int n_in,
                              void* d_out, int out_size, void* d_ws, size_t ws_size,
                              hipStream_t stream) {
    const float* input_data   = (const float*)d_in[0];
    const int*   mask         = (const int*)d_in[1];
    const float* in_proj_w    = (const float*)d_in[2];
    const float* conv_w       = (const float*)d_in[3];
    const float* conv_b       = (const float*)d_in[4];
    const float* xproj_w      = (const float*)d_in[5];
    const float* dtproj_w     = (const float*)d_in[6];
    const float* dtproj_b     = (const float*)d_in[7];
    const float* A_log        = (const float*)d_in[8];
    const float* Dp           = (const float*)d_in[9];
    const float* outproj_w    = (const float*)d_in[10];
    const float* norm_w       = (const float*)d_in[11];
    const float* final_norm_w = (const float*)d_in[12];
    float* out = (float*)d_out;

    const size_t M = (size_t)BQ * SQ;  // 4096
    float* x              = (float*)d_ws;                       // M*DM f32
    unsigned short* xn_bf = (unsigned short*)(x + M * DM);      // M*DM bf16
    float* xz             = (float*)(xn_bf + M * DM);           // M*2DI f32
    float* u              = xz + M * 2 * DI;                    // M*DI f32
    float* xdbl           = u + M * DI;                         // M*64 f32
    float* dtb            = xdbl + M * 64;                      // M*DI f32
    unsigned short* ubf   = (unsigned short*)(dtb + M * DI);    // M*DI bf16
    unsigned short* ybf   = ubf + M * DI;                       // M*DI bf16
    unsigned short* wbf_in  = ybf + M * DI;                     // L*2DI*DM bf16
    unsigned short* wbf_out = wbf_in + (size_t)NLAYERS * 2 * DI * DM;  // L*DM*DI
    unsigned short* wbf_x   = wbf_out + (size_t)NLAYERS * DM * DI;     // L*64*DI

    // weight conversions (per-launch; inputs restored before each timed call)
    {
        int n4 = NLAYERS * 2 * DI * DM / 4;   // 1,048,576
        k_cvt<<<(n4 + 255) / 256, 256, 0, stream>>>(in_proj_w, wbf_in, n4);
        n4 = NLAYERS * DM * DI / 4;           // 262,144
        k_cvt<<<(n4 + 255) / 256, 256, 0, stream>>>(outproj_w, wbf_out, n4);
        n4 = NLAYERS * 64 * DI / 4;           // 32,768
        k_cvt<<<(n4 + 255) / 256, 256, 0, stream>>>(xproj_w, wbf_x, n4);
    }

    // x = transpose(input_data)
    k_transpose<<<dim3(SQ / 32, DM / 32, BQ), dim3(32, 8), 0, stream>>>(input_data, x);

    for (int l = 0; l < NLAYERS; l++) {
        // xn_bf = bf16(rmsnorm(x))
        k_rmsnorm_bf<<<M, 256, 0, stream>>>(x, norm_w + (size_t)l * DM, xn_bf);
        // xz = xn @ in_proj^T   (M x 2048, K=512)  [MFMA]
        k_gemm_bf16<<<dim3(2 * DI / 128, M / 128), 256, 0, stream>>>(
            xn_bf, DM, wbf_in + (size_t)l * 2 * DI * DM, DM, xz, 2 * DI, DM,
            nullptr, 0);
        // u = silu(conv(xz[:, :DI])), fp32 + bf16
        k_conv_silu<<<M, 256, 0, stream>>>(xz, conv_w + (size_t)l * DI * DCONV,
                                           conv_b + (size_t)l * DI, u, ubf);
        // xdbl = u @ xproj^T   (M x 64, K=1024)  [MFMA, N=64]
        k_gemm_bf16_n64<<<M / 128, 256, 0, stream>>>(
            ubf, DI, wbf_x + (size_t)l * 64 * DI, DI, xdbl, 64, DI);
        // dt = softplus(xdbl[:, :32] @ dtproj^T + b)   (M x 1024, K=32) [fp32]
        k_gemm<<<dim3(DI / 64, M / 64), 256, 0, stream>>>(
            xdbl, 64, dtproj_w + (size_t)l * DI * DTR, DTR, dtb, DI, DTR,
            dtproj_b + (size_t)l * DI, 1, nullptr, 0);
        // ybf = bf16( scan(...) * silu(z) )
        k_scan2<<<BQ * (DI / 16), 256, 0, stream>>>(
            xdbl, dtb, u, xz, A_log + (size_t)l * DI * DSTATE, Dp + (size_t)l * DI, ybf);
        // x = x + ybf @ outproj^T   (M x 512, K=1024)  [MFMA + resid]
        k_gemm_bf16<<<dim3(DM / 128, M / 128), 256, 0, stream>>>(
            ybf, DI, wbf_out + (size_t)l * DM * DI, DI, x, DM, DI,
            x, DM);
    }

    // tokens = rmsnorm(x, final_norm_w) -> d_out (fp32)
    k_rmsnorm_f32<<<M, 256, 0, stream>>>(x, final_norm_w, out);
    // emb
    k_emb<<<BQ, 256, 0, stream>>>(out, mask, out + M * DM);
}

// Round 5
// 557.789 us; speedup vs baseline: 2.5466x; 2.5466x over previous
//
#include <hip/hip_runtime.h>
#include <hip/hip_bf16.h>
#include <cmath>

#define BQ 2
#define SQ 2048
#define DM 512
#define DI 1024
#define DSTATE 16
#define DCONV 4
#define DTR 32
#define NLAYERS 2
#define CHUNK 128
#define NCH (SQ / CHUNK)   // 16 chunks

typedef __attribute__((ext_vector_type(8))) short bf16x8;
typedef __attribute__((ext_vector_type(4))) float f32x4;

__device__ __forceinline__ unsigned short f2bf(float f) {
    __hip_bfloat16 h = __float2bfloat16(f);
    return *reinterpret_cast<unsigned short*>(&h);
}

// ---------------------------------------------------------------- transpose
// input_data (B, DM, SQ) -> x (B, SQ, DM)
__global__ __launch_bounds__(256) void k_transpose(const float* __restrict__ in,
                                                   float* __restrict__ out) {
    __shared__ float tile[32][33];
    int b = blockIdx.z;
    int s0 = blockIdx.x * 32, c0 = blockIdx.y * 32;
    int tx = threadIdx.x, ty = threadIdx.y;  // block (32,8)
#pragma unroll
    for (int i = 0; i < 4; i++)
        tile[ty + i * 8][tx] = in[((size_t)b * DM + c0 + ty + i * 8) * SQ + s0 + tx];
    __syncthreads();
#pragma unroll
    for (int i = 0; i < 4; i++)
        out[((size_t)b * SQ + s0 + ty + i * 8) * DM + c0 + tx] = tile[tx][ty + i * 8];
}

// ---------------------------------------------------------------- fp32 -> bf16 convert (n4 = n/4)
__global__ __launch_bounds__(256) void k_cvt(const float* __restrict__ in,
                                             unsigned short* __restrict__ out, int n4) {
    int i = blockIdx.x * 256 + threadIdx.x;
    if (i >= n4) return;
    float4 v = ((const float4*)in)[i];
    ushort4 o;
    o.x = f2bf(v.x); o.y = f2bf(v.y); o.z = f2bf(v.z); o.w = f2bf(v.w);
    ((ushort4*)out)[i] = o;
}

// ---------------------------------------------------------------- rmsnorm (D=512), bf16 output
__global__ __launch_bounds__(256) void k_rmsnorm_bf(const float* __restrict__ x,
                                                    const float* __restrict__ w,
                                                    unsigned short* __restrict__ out) {
    int row = blockIdx.x;
    const float* xr = x + (size_t)row * DM;
    float v0 = xr[threadIdx.x];
    float v1 = xr[threadIdx.x + 256];
    float ss = v0 * v0 + v1 * v1;
#pragma unroll
    for (int off = 32; off >= 1; off >>= 1) ss += __shfl_xor(ss, off);
    __shared__ float wc[4];
    if ((threadIdx.x & 63) == 0) wc[threadIdx.x >> 6] = ss;
    __syncthreads();
    ss = wc[0] + wc[1] + wc[2] + wc[3];
    float r = rsqrtf(ss * (1.0f / DM) + 1e-5f);
    out[(size_t)row * DM + threadIdx.x] = f2bf(v0 * r * w[threadIdx.x]);
    out[(size_t)row * DM + threadIdx.x + 256] = f2bf(v1 * r * w[threadIdx.x + 256]);
}

// ---------------------------------------------------------------- rmsnorm fp32 output (final)
__global__ __launch_bounds__(256) void k_rmsnorm_f32(const float* __restrict__ x,
                                                     const float* __restrict__ w,
                                                     float* __restrict__ out) {
    int row = blockIdx.x;
    const float* xr = x + (size_t)row * DM;
    float v0 = xr[threadIdx.x];
    float v1 = xr[threadIdx.x + 256];
    float ss = v0 * v0 + v1 * v1;
#pragma unroll
    for (int off = 32; off >= 1; off >>= 1) ss += __shfl_xor(ss, off);
    __shared__ float wc[4];
    if ((threadIdx.x & 63) == 0) wc[threadIdx.x >> 6] = ss;
    __syncthreads();
    ss = wc[0] + wc[1] + wc[2] + wc[3];
    float r = rsqrtf(ss * (1.0f / DM) + 1e-5f);
    out[(size_t)row * DM + threadIdx.x] = v0 * r * w[threadIdx.x];
    out[(size_t)row * DM + threadIdx.x + 256] = v1 * r * w[threadIdx.x + 256];
}

// ---------------------------------------------------------------- bf16 MFMA GEMM  C = A @ W^T (+resid)
// A (M,K) bf16 lda, W (N,K) bf16 ldw, C (M,N) fp32 ldc. 128x128 tile, BK=32.
// Slot swizzle: within each row's four 16B k-slices, slot s holds global slice s^(row&3);
// applied to global SOURCE (staging) and LDS READ (same involution) — LDS dest stays linear.
__global__ __launch_bounds__(256) void k_gemm_bf16(const unsigned short* __restrict__ A, int lda,
                                                   const unsigned short* __restrict__ W, int ldw,
                                                   float* __restrict__ C, int ldc, int K,
                                                   const float* __restrict__ resid, int ldr) {
    __shared__ __align__(16) unsigned short As[128 * 32];
    __shared__ __align__(16) unsigned short Bs[128 * 32];
    const int bm = blockIdx.y * 128, bn = blockIdx.x * 128;
    const int tid = threadIdx.x;
    const int w = tid >> 6, l = tid & 63;
    const int wr = w >> 1, wc = w & 1;
    const int lg = l >> 4, lr16 = l & 15;
    f32x4 acc[4][4] = {};
    for (int k0 = 0; k0 < K; k0 += 32) {
        __syncthreads();
#pragma unroll
        for (int i = 0; i < 2; i++) {
            int slot = i * 256 + tid;
            int row = slot >> 2, s = slot & 3;
            int sg = s ^ (row & 3);
            __builtin_amdgcn_global_load_lds(
                (const __attribute__((address_space(1))) unsigned int*)(A + (size_t)(bm + row) * lda + k0 + sg * 8),
                (__attribute__((address_space(3))) unsigned int*)(As + slot * 8), 16, 0, 0);
            __builtin_amdgcn_global_load_lds(
                (const __attribute__((address_space(1))) unsigned int*)(W + (size_t)(bn + row) * ldw + k0 + sg * 8),
                (__attribute__((address_space(3))) unsigned int*)(Bs + slot * 8), 16, 0, 0);
        }
        asm volatile("s_waitcnt vmcnt(0)" ::: "memory");
        __syncthreads();
        bf16x8 fa[4], fb[4];
#pragma unroll
        for (int f = 0; f < 4; f++) {
            int ar = wr * 64 + f * 16 + lr16;
            fa[f] = *(const bf16x8*)&As[ar * 32 + (lg ^ (ar & 3)) * 8];
            int br = wc * 64 + f * 16 + lr16;
            fb[f] = *(const bf16x8*)&Bs[br * 32 + (lg ^ (br & 3)) * 8];
        }
#pragma unroll
        for (int fi = 0; fi < 4; fi++)
#pragma unroll
            for (int fj = 0; fj < 4; fj++)
                acc[fi][fj] = __builtin_amdgcn_mfma_f32_16x16x32_bf16(fa[fi], fb[fj], acc[fi][fj], 0, 0, 0);
    }
#pragma unroll
    for (int fi = 0; fi < 4; fi++)
#pragma unroll
        for (int fj = 0; fj < 4; fj++)
#pragma unroll
            for (int r = 0; r < 4; r++) {
                int m = bm + wr * 64 + fi * 16 + lg * 4 + r;
                int n = bn + wc * 64 + fj * 16 + lr16;
                float v = acc[fi][fj][r];
                if (resid) v += resid[(size_t)m * ldr + n];
                C[(size_t)m * ldc + n] = v;
            }
}

// ---------------------------------------------------------------- bf16 MFMA GEMM, N=64 (x_proj)
// 128-row M tile x 64 N; 4 waves stacked on M (32 rows each).
__global__ __launch_bounds__(256) void k_gemm_bf16_n64(const unsigned short* __restrict__ A, int lda,
                                                       const unsigned short* __restrict__ W, int ldw,
                                                       float* __restrict__ C, int ldc, int K) {
    __shared__ __align__(16) unsigned short As[128 * 32];
    __shared__ __align__(16) unsigned short Bs[64 * 32];
    const int bm = blockIdx.x * 128;
    const int tid = threadIdx.x;
    const int w = tid >> 6, l = tid & 63;
    const int lg = l >> 4, lr16 = l & 15;
    f32x4 acc[2][4] = {};
    for (int k0 = 0; k0 < K; k0 += 32) {
        __syncthreads();
#pragma unroll
        for (int i = 0; i < 2; i++) {
            int slot = i * 256 + tid;
            int row = slot >> 2, s = slot & 3;
            int sg = s ^ (row & 3);
            __builtin_amdgcn_global_load_lds(
                (const __attribute__((address_space(1))) unsigned int*)(A + (size_t)(bm + row) * lda + k0 + sg * 8),
                (__attribute__((address_space(3))) unsigned int*)(As + slot * 8), 16, 0, 0);
        }
        {
            int slot = tid;
            int row = slot >> 2, s = slot & 3;
            int sg = s ^ (row & 3);
            __builtin_amdgcn_global_load_lds(
                (const __attribute__((address_space(1))) unsigned int*)(W + (size_t)row * ldw + k0 + sg * 8),
                (__attribute__((address_space(3))) unsigned int*)(Bs + slot * 8), 16, 0, 0);
        }
        asm volatile("s_waitcnt vmcnt(0)" ::: "memory");
        __syncthreads();
        bf16x8 fa[2], fb[4];
#pragma unroll
        for (int f = 0; f < 2; f++) {
            int ar = w * 32 + f * 16 + lr16;
            fa[f] = *(const bf16x8*)&As[ar * 32 + (lg ^ (ar & 3)) * 8];
        }
#pragma unroll
        for (int f = 0; f < 4; f++) {
            int br = f * 16 + lr16;
            fb[f] = *(const bf16x8*)&Bs[br * 32 + (lg ^ (br & 3)) * 8];
        }
#pragma unroll
        for (int fi = 0; fi < 2; fi++)
#pragma unroll
            for (int fj = 0; fj < 4; fj++)
                acc[fi][fj] = __builtin_amdgcn_mfma_f32_16x16x32_bf16(fa[fi], fb[fj], acc[fi][fj], 0, 0, 0);
    }
#pragma unroll
    for (int fi = 0; fi < 2; fi++)
#pragma unroll
        for (int fj = 0; fj < 4; fj++)
#pragma unroll
            for (int r = 0; r < 4; r++) {
                int m = bm + w * 32 + fi * 16 + lg * 4 + r;
                int n = fj * 16 + lr16;
                C[(size_t)m * ldc + n] = acc[fi][fj][r];
            }
}

// ---------------------------------------------------------------- fp32 GEMM (small: dt projection)
__global__ __launch_bounds__(256) void k_gemm(const float* __restrict__ A, int lda,
                                              const float* __restrict__ W, int ldw,
                                              float* __restrict__ C, int ldc, int K,
                                              const float* __restrict__ bias, int act,
                                              const float* __restrict__ resid, int ldr) {
    __shared__ float As[16][64];
    __shared__ float Bs[16][64];
    int bm = blockIdx.y * 64, bn = blockIdx.x * 64;
    int tid = threadIdx.x;
    int tx = tid & 15, ty = tid >> 4;
    int lr = tid >> 2, lk = (tid & 3) << 2;
    float acc[4][4] = {};
    for (int k0 = 0; k0 < K; k0 += 16) {
        float4 av = *(const float4*)&A[(size_t)(bm + lr) * lda + k0 + lk];
        float4 wv = *(const float4*)&W[(size_t)(bn + lr) * ldw + k0 + lk];
        __syncthreads();
        As[lk + 0][lr] = av.x; As[lk + 1][lr] = av.y;
        As[lk + 2][lr] = av.z; As[lk + 3][lr] = av.w;
        Bs[lk + 0][lr] = wv.x; Bs[lk + 1][lr] = wv.y;
        Bs[lk + 2][lr] = wv.z; Bs[lk + 3][lr] = wv.w;
        __syncthreads();
#pragma unroll
        for (int k = 0; k < 16; k++) {
            float a[4], bb[4];
#pragma unroll
            for (int i = 0; i < 4; i++) a[i] = As[k][ty * 4 + i];
#pragma unroll
            for (int j = 0; j < 4; j++) bb[j] = Bs[k][tx * 4 + j];
#pragma unroll
            for (int i = 0; i < 4; i++)
#pragma unroll
                for (int j = 0; j < 4; j++) acc[i][j] += a[i] * bb[j];
        }
    }
#pragma unroll
    for (int i = 0; i < 4; i++) {
        int m = bm + ty * 4 + i;
#pragma unroll
        for (int j = 0; j < 4; j++) {
            int n = bn + tx * 4 + j;
            float v = acc[i][j];
            if (bias) v += bias[n];
            if (act == 1) v = fmaxf(v, 0.f) + log1pf(expf(-fabsf(v)));
            if (resid) v += resid[(size_t)m * ldr + n];
            C[(size_t)m * ldc + n] = v;
        }
    }
}

// ---------------------------------------------------------------- causal depthwise conv (k=4) + silu
// writes fp32 u (for scan) and bf16 u (for x_proj MFMA)
__global__ __launch_bounds__(256) void k_conv_silu(const float* __restrict__ xz,
                                                   const float* __restrict__ cw,
                                                   const float* __restrict__ cb,
                                                   float* __restrict__ u,
                                                   unsigned short* __restrict__ ubf) {
    int bt = blockIdx.x;       // b*SQ + t
    int t = bt & (SQ - 1);
#pragma unroll
    for (int dd = 0; dd < 4; dd++) {
        int d = dd * 256 + threadIdx.x;
        float acc = cb[d];
#pragma unroll
        for (int k = 0; k < DCONV; k++) {
            int tk = t + k - (DCONV - 1);
            if (tk >= 0)
                acc += xz[((size_t)(bt + k - (DCONV - 1))) * (2 * DI) + d] * cw[d * DCONV + k];
        }
        float sig = 1.f / (1.f + expf(-acc));
        float v = acc * sig;
        u[(size_t)bt * DI + d] = v;
        ubf[(size_t)bt * DI + d] = f2bf(v);
    }
}

// ---------------------------------------------------------------- chunked scan, phase 1
// per (b, chunk, d, s): chunk-local scan from h=0 -> hend; D = exp(a * sum dt)
// block = 256 (16 s x 16 dl); grid = B * NCH * (DI/16)
__global__ __launch_bounds__(256) void k_scan_p1(const float* __restrict__ xdbl,
                                                 const float* __restrict__ dt,
                                                 const float* __restrict__ u,
                                                 const float* __restrict__ A_log,
                                                 float* __restrict__ hend,
                                                 float* __restrict__ dchunk) {
    int bc = blockIdx.x >> 6;          // b*NCH + c
    int d0 = (blockIdx.x & 63) << 4;
    int b = bc >> 4;                   // NCH == 16
    int c = bc & (NCH - 1);
    int tid = threadIdx.x;
    int s = tid & 15, dl = tid >> 4;
    int d = d0 + dl;
    float a = -expf(A_log[(size_t)d * DSTATE + s]);
    float h = 0.f, sumdt = 0.f;
    __shared__ float sdt[64][16], su[64][16], sB[64][16];
    int tbase = c * CHUNK;
    for (int t0 = 0; t0 < CHUNK; t0 += 64) {
        __syncthreads();
#pragma unroll
        for (int i = 0; i < 4; i++) {
            int e = i * 256 + tid;
            int tt = e >> 4, j = e & 15;
            size_t rowm = (size_t)(b * SQ + tbase + t0 + tt);
            sdt[tt][j] = dt[rowm * DI + d0 + j];
            su[tt][j]  = u[rowm * DI + d0 + j];
            sB[tt][j]  = xdbl[rowm * 64 + DTR + j];
        }
        __syncthreads();
        for (int tt = 0; tt < 64; tt++) {
            float dtv = sdt[tt][dl];
            float uv  = su[tt][dl];
            sumdt += dtv;
            float dA = __expf(dtv * a);
            h = dA * h + dtv * uv * sB[tt][s];
        }
    }
    size_t o = (((size_t)bc * DI) + d) * DSTATE + s;
    hend[o] = h;
    dchunk[o] = __expf(a * sumdt);
}

// ---------------------------------------------------------------- chunked scan, phase 2
// per (b,d,s): scan over NCH chunks -> hstart per chunk. 32768 threads.
__global__ __launch_bounds__(256) void k_scan_p2(const float* __restrict__ hend,
                                                 const float* __restrict__ dchunk,
                                                 float* __restrict__ hstart) {
    int tid = blockIdx.x * 256 + threadIdx.x;   // 0 .. B*DI*DSTATE-1
    int b = tid >> 14;                          // /(DI*DSTATE = 16384)
    int ds = tid & 16383;                       // d*16 + s
    float h = 0.f;
#pragma unroll
    for (int c = 0; c < NCH; c++) {
        size_t o = (((size_t)(b * NCH + c)) << 14) + ds;
        hstart[o] = h;
        h = dchunk[o] * h + hend[o];
    }
}

// ---------------------------------------------------------------- chunked scan, phase 3
// per chunk: exact recurrence seeded with hstart; y + u*Dp + silu(z) gate -> ybf
__global__ __launch_bounds__(256) void k_scan_p3(const float* __restrict__ xdbl,
                                                 const float* __restrict__ dt,
                                                 const float* __restrict__ u,
                                                 const float* __restrict__ xz,
                                                 const float* __restrict__ A_log,
                                                 const float* __restrict__ Dp,
                                                 const float* __restrict__ hstart,
                                                 unsigned short* __restrict__ yout) {
    int bc = blockIdx.x >> 6;
    int d0 = (blockIdx.x & 63) << 4;
    int b = bc >> 4;
    int c = bc & (NCH - 1);
    int tid = threadIdx.x;
    int s = tid & 15, dl = tid >> 4;
    int d = d0 + dl;
    float a = -expf(A_log[(size_t)d * DSTATE + s]);
    float h = hstart[(((size_t)bc) << 14) + (d << 4) + s];
    float Dv = Dp[d];
    __shared__ float sdt[64][16], su[64][16], sz[64][16], sB[64][16], sC[64][16];
    int tbase = c * CHUNK;
    for (int t0 = 0; t0 < CHUNK; t0 += 64) {
        __syncthreads();
#pragma unroll
        for (int i = 0; i < 4; i++) {
            int e = i * 256 + tid;
            int tt = e >> 4, j = e & 15;
            size_t rowm = (size_t)(b * SQ + tbase + t0 + tt);
            sdt[tt][j] = dt[rowm * DI + d0 + j];
            su[tt][j]  = u[rowm * DI + d0 + j];
            sz[tt][j]  = xz[rowm * (2 * DI) + DI + d0 + j];
            sB[tt][j]  = xdbl[rowm * 64 + DTR + j];
            sC[tt][j]  = xdbl[rowm * 64 + DTR + DSTATE + j];
        }
        __syncthreads();
        for (int tt = 0; tt < 64; tt++) {
            float dtv = sdt[tt][dl];
            float uv  = su[tt][dl];
            float dA = __expf(dtv * a);
            h = dA * h + dtv * uv * sB[tt][s];
            float y = h * sC[tt][s];
            y += __shfl_xor(y, 1);
            y += __shfl_xor(y, 2);
            y += __shfl_xor(y, 4);
            y += __shfl_xor(y, 8);
            if (s == 0) {
                y += uv * Dv;
                float zv = sz[tt][dl];
                float g = zv / (1.f + __expf(-zv));
                yout[(size_t)(b * SQ + tbase + t0 + tt) * DI + d] = f2bf(y * g);
            }
        }
    }
}

// ---------------------------------------------------------------- emb gather (mask is int32)
__global__ __launch_bounds__(256) void k_emb(const float* __restrict__ tokens,
                                             const int* __restrict__ mask,
                                             float* __restrict__ emb) {
    int b = blockIdx.x;
    int cnt = 0;
    for (int i = threadIdx.x; i < SQ; i += 256) cnt += mask[b * SQ + i] ? 1 : 0;
#pragma unroll
    for (int off = 32; off >= 1; off >>= 1) cnt += __shfl_xor(cnt, off);
    __shared__ int wc[4];
    if ((threadIdx.x & 63) == 0) wc[threadIdx.x >> 6] = cnt;
    __syncthreads();
    int total = wc[0] + wc[1] + wc[2] + wc[3];
    int idx = total > 0 ? total - 1 : 0;
    for (int i = threadIdx.x; i < DM; i += 256)
        emb[b * DM + i] = tokens[((size_t)b * SQ + idx) * DM + i];
}

// ---------------------------------------------------------------- host
extern "C" void kernel_launch(void* const* d_in, const int* in_sizes, int n_in,
                              void* d_out, int out_size, void* d_ws, size_t ws_size,
                              hipStream_t stream) {
    const float* input_data   = (const float*)d_in[0];
    const int*   mask         = (const int*)d_in[1];
    const float* in_proj_w    = (const float*)d_in[2];
    const float* conv_w       = (const float*)d_in[3];
    const float* conv_b       = (const float*)d_in[4];
    const float* xproj_w      = (const float*)d_in[5];
    const float* dtproj_w     = (const float*)d_in[6];
    const float* dtproj_b     = (const float*)d_in[7];
    const float* A_log        = (const float*)d_in[8];
    const float* Dp           = (const float*)d_in[9];
    const float* outproj_w    = (const float*)d_in[10];
    const float* norm_w       = (const float*)d_in[11];
    const float* final_norm_w = (const float*)d_in[12];
    float* out = (float*)d_out;

    const size_t M = (size_t)BQ * SQ;  // 4096
    const size_t CS = (size_t)BQ * NCH * DI * DSTATE;  // chunk-state size: 524288
    float* x              = (float*)d_ws;                       // M*DM f32
    unsigned short* xn_bf = (unsigned short*)(x + M * DM);      // M*DM bf16
    float* xz             = (float*)(xn_bf + M * DM);           // M*2DI f32
    float* u              = xz + M * 2 * DI;                    // M*DI f32
    float* xdbl           = u + M * DI;                         // M*64 f32
    float* dtb            = xdbl + M * 64;                      // M*DI f32
    unsigned short* ubf   = (unsigned short*)(dtb + M * DI);    // M*DI bf16
    unsigned short* ybf   = ubf + M * DI;                       // M*DI bf16
    float* hend           = (float*)(ybf + M * DI);             // CS f32
    float* dchunk         = hend + CS;                          // CS f32
    float* hstart         = dchunk + CS;                        // CS f32
    unsigned short* wbf_in  = (unsigned short*)(hstart + CS);   // L*2DI*DM bf16
    unsigned short* wbf_out = wbf_in + (size_t)NLAYERS * 2 * DI * DM;  // L*DM*DI
    unsigned short* wbf_x   = wbf_out + (size_t)NLAYERS * DM * DI;     // L*64*DI

    // weight conversions (per-launch; inputs restored before each timed call)
    {
        int n4 = NLAYERS * 2 * DI * DM / 4;   // 1,048,576 -> actually /4 = 524288
        k_cvt<<<(n4 + 255) / 256, 256, 0, stream>>>(in_proj_w, wbf_in, n4);
        n4 = NLAYERS * DM * DI / 4;
        k_cvt<<<(n4 + 255) / 256, 256, 0, stream>>>(outproj_w, wbf_out, n4);
        n4 = NLAYERS * 64 * DI / 4;
        k_cvt<<<(n4 + 255) / 256, 256, 0, stream>>>(xproj_w, wbf_x, n4);
    }

    // x = transpose(input_data)
    k_transpose<<<dim3(SQ / 32, DM / 32, BQ), dim3(32, 8), 0, stream>>>(input_data, x);

    for (int l = 0; l < NLAYERS; l++) {
        // xn_bf = bf16(rmsnorm(x))
        k_rmsnorm_bf<<<M, 256, 0, stream>>>(x, norm_w + (size_t)l * DM, xn_bf);
        // xz = xn @ in_proj^T   (M x 2048, K=512)  [MFMA]
        k_gemm_bf16<<<dim3(2 * DI / 128, M / 128), 256, 0, stream>>>(
            xn_bf, DM, wbf_in + (size_t)l * 2 * DI * DM, DM, xz, 2 * DI, DM,
            nullptr, 0);
        // u = silu(conv(xz[:, :DI])), fp32 + bf16
        k_conv_silu<<<M, 256, 0, stream>>>(xz, conv_w + (size_t)l * DI * DCONV,
                                           conv_b + (size_t)l * DI, u, ubf);
        // xdbl = u @ xproj^T   (M x 64, K=1024)  [MFMA, N=64]
        k_gemm_bf16_n64<<<M / 128, 256, 0, stream>>>(
            ubf, DI, wbf_x + (size_t)l * 64 * DI, DI, xdbl, 64, DI);
        // dt = softplus(xdbl[:, :32] @ dtproj^T + b)   (M x 1024, K=32) [fp32]
        k_gemm<<<dim3(DI / 64, M / 64), 256, 0, stream>>>(
            xdbl, 64, dtproj_w + (size_t)l * DI * DTR, DTR, dtb, DI, DTR,
            dtproj_b + (size_t)l * DI, 1, nullptr, 0);
        // chunked scan: p1 local scans + decay, p2 cross-chunk combine, p3 seeded scan + gate
        k_scan_p1<<<BQ * NCH * (DI / 16), 256, 0, stream>>>(
            xdbl, dtb, u, A_log + (size_t)l * DI * DSTATE, hend, dchunk);
        k_scan_p2<<<(BQ * DI * DSTATE) / 256, 256, 0, stream>>>(hend, dchunk, hstart);
        k_scan_p3<<<BQ * NCH * (DI / 16), 256, 0, stream>>>(
            xdbl, dtb, u, xz, A_log + (size_t)l * DI * DSTATE, Dp + (size_t)l * DI,
            hstart, ybf);
        // x = x + ybf @ outproj^T   (M x 512, K=1024)  [MFMA + resid]
        k_gemm_bf16<<<dim3(DM / 128, M / 128), 256, 0, stream>>>(
            ybf, DI, wbf_out + (size_t)l * DM * DI, DI, x, DM, DI,
            x, DM);
    }

    // tokens = rmsnorm(x, final_norm_w) -> d_out (fp32)
    k_rmsnorm_f32<<<M, 256, 0, stream>>>(x, final_norm_w, out);
    // emb
    k_emb<<<BQ, 256, 0, stream>>>(out, mask, out + M * DM);
}

// Round 6
// 468.597 us; speedup vs baseline: 3.0313x; 1.1903x over previous
//
#include <hip/hip_runtime.h>
#include <hip/hip_bf16.h>
#include <cmath>

#define BQ 2
#define SQ 2048
#define DM 512
#define DI 1024
#define DSTATE 16
#define DCONV 4
#define DTR 32
#define NLAYERS 2
#define CHUNK 64
#define NCH (SQ / CHUNK)   // 32 chunks

typedef __attribute__((ext_vector_type(8))) short bf16x8;
typedef __attribute__((ext_vector_type(4))) float f32x4;

__device__ __forceinline__ unsigned short f2bf(float f) {
    __hip_bfloat16 h = __float2bfloat16(f);
    return *reinterpret_cast<unsigned short*>(&h);
}

// ---------------------------------------------------------------- transpose
// input_data (B, DM, SQ) -> x (B, SQ, DM)
__global__ __launch_bounds__(256) void k_transpose(const float* __restrict__ in,
                                                   float* __restrict__ out) {
    __shared__ float tile[32][33];
    int b = blockIdx.z;
    int s0 = blockIdx.x * 32, c0 = blockIdx.y * 32;
    int tx = threadIdx.x, ty = threadIdx.y;  // block (32,8)
#pragma unroll
    for (int i = 0; i < 4; i++)
        tile[ty + i * 8][tx] = in[((size_t)b * DM + c0 + ty + i * 8) * SQ + s0 + tx];
    __syncthreads();
#pragma unroll
    for (int i = 0; i < 4; i++)
        out[((size_t)b * SQ + s0 + ty + i * 8) * DM + c0 + tx] = tile[tx][ty + i * 8];
}

// ---------------------------------------------------------------- fp32 -> bf16 convert (n4 = n/4)
__global__ __launch_bounds__(256) void k_cvt(const float* __restrict__ in,
                                             unsigned short* __restrict__ out, int n4) {
    int i = blockIdx.x * 256 + threadIdx.x;
    if (i >= n4) return;
    float4 v = ((const float4*)in)[i];
    ushort4 o;
    o.x = f2bf(v.x); o.y = f2bf(v.y); o.z = f2bf(v.z); o.w = f2bf(v.w);
    ((ushort4*)out)[i] = o;
}

// ---------------------------------------------------------------- rmsnorm (D=512), bf16 output
__global__ __launch_bounds__(256) void k_rmsnorm_bf(const float* __restrict__ x,
                                                    const float* __restrict__ w,
                                                    unsigned short* __restrict__ out) {
    int row = blockIdx.x;
    const float* xr = x + (size_t)row * DM;
    float v0 = xr[threadIdx.x];
    float v1 = xr[threadIdx.x + 256];
    float ss = v0 * v0 + v1 * v1;
#pragma unroll
    for (int off = 32; off >= 1; off >>= 1) ss += __shfl_xor(ss, off);
    __shared__ float wc[4];
    if ((threadIdx.x & 63) == 0) wc[threadIdx.x >> 6] = ss;
    __syncthreads();
    ss = wc[0] + wc[1] + wc[2] + wc[3];
    float r = rsqrtf(ss * (1.0f / DM) + 1e-5f);
    out[(size_t)row * DM + threadIdx.x] = f2bf(v0 * r * w[threadIdx.x]);
    out[(size_t)row * DM + threadIdx.x + 256] = f2bf(v1 * r * w[threadIdx.x + 256]);
}

// ---------------------------------------------------------------- rmsnorm fp32 output (final)
__global__ __launch_bounds__(256) void k_rmsnorm_f32(const float* __restrict__ x,
                                                     const float* __restrict__ w,
                                                     float* __restrict__ out) {
    int row = blockIdx.x;
    const float* xr = x + (size_t)row * DM;
    float v0 = xr[threadIdx.x];
    float v1 = xr[threadIdx.x + 256];
    float ss = v0 * v0 + v1 * v1;
#pragma unroll
    for (int off = 32; off >= 1; off >>= 1) ss += __shfl_xor(ss, off);
    __shared__ float wc[4];
    if ((threadIdx.x & 63) == 0) wc[threadIdx.x >> 6] = ss;
    __syncthreads();
    ss = wc[0] + wc[1] + wc[2] + wc[3];
    float r = rsqrtf(ss * (1.0f / DM) + 1e-5f);
    out[(size_t)row * DM + threadIdx.x] = v0 * r * w[threadIdx.x];
    out[(size_t)row * DM + threadIdx.x + 256] = v1 * r * w[threadIdx.x + 256];
}

// ---------------------------------------------------------------- bf16 MFMA GEMM  C = A @ W^T (+resid)
__global__ __launch_bounds__(256) void k_gemm_bf16(const unsigned short* __restrict__ A, int lda,
                                                   const unsigned short* __restrict__ W, int ldw,
                                                   float* __restrict__ C, int ldc, int K,
                                                   const float* __restrict__ resid, int ldr) {
    __shared__ __align__(16) unsigned short As[128 * 32];
    __shared__ __align__(16) unsigned short Bs[128 * 32];
    const int bm = blockIdx.y * 128, bn = blockIdx.x * 128;
    const int tid = threadIdx.x;
    const int w = tid >> 6, l = tid & 63;
    const int wr = w >> 1, wc = w & 1;
    const int lg = l >> 4, lr16 = l & 15;
    f32x4 acc[4][4] = {};
    for (int k0 = 0; k0 < K; k0 += 32) {
        __syncthreads();
#pragma unroll
        for (int i = 0; i < 2; i++) {
            int slot = i * 256 + tid;
            int row = slot >> 2, s = slot & 3;
            int sg = s ^ (row & 3);
            __builtin_amdgcn_global_load_lds(
                (const __attribute__((address_space(1))) unsigned int*)(A + (size_t)(bm + row) * lda + k0 + sg * 8),
                (__attribute__((address_space(3))) unsigned int*)(As + slot * 8), 16, 0, 0);
            __builtin_amdgcn_global_load_lds(
                (const __attribute__((address_space(1))) unsigned int*)(W + (size_t)(bn + row) * ldw + k0 + sg * 8),
                (__attribute__((address_space(3))) unsigned int*)(Bs + slot * 8), 16, 0, 0);
        }
        asm volatile("s_waitcnt vmcnt(0)" ::: "memory");
        __syncthreads();
        bf16x8 fa[4], fb[4];
#pragma unroll
        for (int f = 0; f < 4; f++) {
            int ar = wr * 64 + f * 16 + lr16;
            fa[f] = *(const bf16x8*)&As[ar * 32 + (lg ^ (ar & 3)) * 8];
            int br = wc * 64 + f * 16 + lr16;
            fb[f] = *(const bf16x8*)&Bs[br * 32 + (lg ^ (br & 3)) * 8];
        }
#pragma unroll
        for (int fi = 0; fi < 4; fi++)
#pragma unroll
            for (int fj = 0; fj < 4; fj++)
                acc[fi][fj] = __builtin_amdgcn_mfma_f32_16x16x32_bf16(fa[fi], fb[fj], acc[fi][fj], 0, 0, 0);
    }
#pragma unroll
    for (int fi = 0; fi < 4; fi++)
#pragma unroll
        for (int fj = 0; fj < 4; fj++)
#pragma unroll
            for (int r = 0; r < 4; r++) {
                int m = bm + wr * 64 + fi * 16 + lg * 4 + r;
                int n = bn + wc * 64 + fj * 16 + lr16;
                float v = acc[fi][fj][r];
                if (resid) v += resid[(size_t)m * ldr + n];
                C[(size_t)m * ldc + n] = v;
            }
}

// ---------------------------------------------------------------- bf16 MFMA GEMM, N=64 (x_proj)
__global__ __launch_bounds__(256) void k_gemm_bf16_n64(const unsigned short* __restrict__ A, int lda,
                                                       const unsigned short* __restrict__ W, int ldw,
                                                       float* __restrict__ C, int ldc, int K) {
    __shared__ __align__(16) unsigned short As[128 * 32];
    __shared__ __align__(16) unsigned short Bs[64 * 32];
    const int bm = blockIdx.x * 128;
    const int tid = threadIdx.x;
    const int w = tid >> 6, l = tid & 63;
    const int lg = l >> 4, lr16 = l & 15;
    f32x4 acc[2][4] = {};
    for (int k0 = 0; k0 < K; k0 += 32) {
        __syncthreads();
#pragma unroll
        for (int i = 0; i < 2; i++) {
            int slot = i * 256 + tid;
            int row = slot >> 2, s = slot & 3;
            int sg = s ^ (row & 3);
            __builtin_amdgcn_global_load_lds(
                (const __attribute__((address_space(1))) unsigned int*)(A + (size_t)(bm + row) * lda + k0 + sg * 8),
                (__attribute__((address_space(3))) unsigned int*)(As + slot * 8), 16, 0, 0);
        }
        {
            int slot = tid;
            int row = slot >> 2, s = slot & 3;
            int sg = s ^ (row & 3);
            __builtin_amdgcn_global_load_lds(
                (const __attribute__((address_space(1))) unsigned int*)(W + (size_t)row * ldw + k0 + sg * 8),
                (__attribute__((address_space(3))) unsigned int*)(Bs + slot * 8), 16, 0, 0);
        }
        asm volatile("s_waitcnt vmcnt(0)" ::: "memory");
        __syncthreads();
        bf16x8 fa[2], fb[4];
#pragma unroll
        for (int f = 0; f < 2; f++) {
            int ar = w * 32 + f * 16 + lr16;
            fa[f] = *(const bf16x8*)&As[ar * 32 + (lg ^ (ar & 3)) * 8];
        }
#pragma unroll
        for (int f = 0; f < 4; f++) {
            int br = f * 16 + lr16;
            fb[f] = *(const bf16x8*)&Bs[br * 32 + (lg ^ (br & 3)) * 8];
        }
#pragma unroll
        for (int fi = 0; fi < 2; fi++)
#pragma unroll
            for (int fj = 0; fj < 4; fj++)
                acc[fi][fj] = __builtin_amdgcn_mfma_f32_16x16x32_bf16(fa[fi], fb[fj], acc[fi][fj], 0, 0, 0);
    }
#pragma unroll
    for (int fi = 0; fi < 2; fi++)
#pragma unroll
        for (int fj = 0; fj < 4; fj++)
#pragma unroll
            for (int r = 0; r < 4; r++) {
                int m = bm + w * 32 + fi * 16 + lg * 4 + r;
                int n = fj * 16 + lr16;
                C[(size_t)m * ldc + n] = acc[fi][fj][r];
            }
}

// ---------------------------------------------------------------- fp32 GEMM (small: dt projection)
__global__ __launch_bounds__(256) void k_gemm(const float* __restrict__ A, int lda,
                                              const float* __restrict__ W, int ldw,
                                              float* __restrict__ C, int ldc, int K,
                                              const float* __restrict__ bias, int act,
                                              const float* __restrict__ resid, int ldr) {
    __shared__ float As[16][64];
    __shared__ float Bs[16][64];
    int bm = blockIdx.y * 64, bn = blockIdx.x * 64;
    int tid = threadIdx.x;
    int tx = tid & 15, ty = tid >> 4;
    int lr = tid >> 2, lk = (tid & 3) << 2;
    float acc[4][4] = {};
    for (int k0 = 0; k0 < K; k0 += 16) {
        float4 av = *(const float4*)&A[(size_t)(bm + lr) * lda + k0 + lk];
        float4 wv = *(const float4*)&W[(size_t)(bn + lr) * ldw + k0 + lk];
        __syncthreads();
        As[lk + 0][lr] = av.x; As[lk + 1][lr] = av.y;
        As[lk + 2][lr] = av.z; As[lk + 3][lr] = av.w;
        Bs[lk + 0][lr] = wv.x; Bs[lk + 1][lr] = wv.y;
        Bs[lk + 2][lr] = wv.z; Bs[lk + 3][lr] = wv.w;
        __syncthreads();
#pragma unroll
        for (int k = 0; k < 16; k++) {
            float a[4], bb[4];
#pragma unroll
            for (int i = 0; i < 4; i++) a[i] = As[k][ty * 4 + i];
#pragma unroll
            for (int j = 0; j < 4; j++) bb[j] = Bs[k][tx * 4 + j];
#pragma unroll
            for (int i = 0; i < 4; i++)
#pragma unroll
                for (int j = 0; j < 4; j++) acc[i][j] += a[i] * bb[j];
        }
    }
#pragma unroll
    for (int i = 0; i < 4; i++) {
        int m = bm + ty * 4 + i;
#pragma unroll
        for (int j = 0; j < 4; j++) {
            int n = bn + tx * 4 + j;
            float v = acc[i][j];
            if (bias) v += bias[n];
            if (act == 1) v = fmaxf(v, 0.f) + log1pf(expf(-fabsf(v)));
            if (resid) v += resid[(size_t)m * ldr + n];
            C[(size_t)m * ldc + n] = v;
        }
    }
}

// ---------------------------------------------------------------- causal depthwise conv (k=4) + silu
__global__ __launch_bounds__(256) void k_conv_silu(const float* __restrict__ xz,
                                                   const float* __restrict__ cw,
                                                   const float* __restrict__ cb,
                                                   float* __restrict__ u,
                                                   unsigned short* __restrict__ ubf) {
    int bt = blockIdx.x;       // b*SQ + t
    int t = bt & (SQ - 1);
#pragma unroll
    for (int dd = 0; dd < 4; dd++) {
        int d = dd * 256 + threadIdx.x;
        float acc = cb[d];
#pragma unroll
        for (int k = 0; k < DCONV; k++) {
            int tk = t + k - (DCONV - 1);
            if (tk >= 0)
                acc += xz[((size_t)(bt + k - (DCONV - 1))) * (2 * DI) + d] * cw[d * DCONV + k];
        }
        float sig = 1.f / (1.f + expf(-acc));
        float v = acc * sig;
        u[(size_t)bt * DI + d] = v;
        ubf[(size_t)bt * DI + d] = f2bf(v);
    }
}

// ---------------------------------------------------------------- chunked scan, phase 1
// 4 states/lane: block 256 = 4 q x 64 dl; grid = B * NCH * (DI/64)
__global__ __launch_bounds__(256) void k_scan_p1(const float* __restrict__ xdbl,
                                                 const float* __restrict__ dt,
                                                 const float* __restrict__ u,
                                                 const float* __restrict__ A_log,
                                                 float* __restrict__ hend,
                                                 float* __restrict__ dchunk) {
    int bc = blockIdx.x >> 4;          // b*NCH + c   (DI/64 == 16)
    int d0 = (blockIdx.x & 15) << 6;
    int b = bc >> 5;                   // NCH == 32
    int c = bc & (NCH - 1);
    int tid = threadIdx.x;
    int q = tid & 3, dl = tid >> 2;
    int d = d0 + dl;
    float4 av = *(const float4*)&A_log[((size_t)d << 4) + 4 * q];
    float a0 = -expf(av.x), a1 = -expf(av.y), a2 = -expf(av.z), a3 = -expf(av.w);
    float h0 = 0.f, h1 = 0.f, h2 = 0.f, h3 = 0.f, sumdt = 0.f;
    __shared__ float sdt[32][65], su[32][65];
    __shared__ __align__(16) float sB[32][16];
    int tbase = c * CHUNK;
    for (int t0 = 0; t0 < CHUNK; t0 += 32) {
        __syncthreads();
#pragma unroll
        for (int i = 0; i < 8; i++) {
            int e = i * 256 + tid;
            int tt = e >> 6, j = e & 63;
            size_t rowm = (size_t)(b * SQ + tbase + t0 + tt);
            sdt[tt][j] = dt[rowm * DI + d0 + j];
            su[tt][j]  = u[rowm * DI + d0 + j];
        }
#pragma unroll
        for (int i = 0; i < 2; i++) {
            int e = i * 256 + tid;
            int tt = e >> 4, j = e & 15;
            size_t rowm = (size_t)(b * SQ + tbase + t0 + tt);
            sB[tt][j] = xdbl[rowm * 64 + DTR + j];
        }
        __syncthreads();
        for (int tt = 0; tt < 32; tt++) {
            float dtv = sdt[tt][dl], uv = su[tt][dl];
            float dtu = dtv * uv;
            sumdt += dtv;
            float4 Bv = *(const float4*)&sB[tt][4 * q];
            h0 = __expf(dtv * a0) * h0 + dtu * Bv.x;
            h1 = __expf(dtv * a1) * h1 + dtu * Bv.y;
            h2 = __expf(dtv * a2) * h2 + dtu * Bv.z;
            h3 = __expf(dtv * a3) * h3 + dtu * Bv.w;
        }
    }
    size_t o = ((size_t)bc << 14) + ((size_t)d << 4) + 4 * q;
    *(float4*)&hend[o] = make_float4(h0, h1, h2, h3);
    *(float4*)&dchunk[o] = make_float4(__expf(a0 * sumdt), __expf(a1 * sumdt),
                                       __expf(a2 * sumdt), __expf(a3 * sumdt));
}

// ---------------------------------------------------------------- chunked scan, phase 2
// per (b,d,s): scan over NCH chunks -> hstart per chunk. 32768 threads.
__global__ __launch_bounds__(256) void k_scan_p2(const float* __restrict__ hend,
                                                 const float* __restrict__ dchunk,
                                                 float* __restrict__ hstart) {
    int tid = blockIdx.x * 256 + threadIdx.x;   // 0 .. B*DI*DSTATE-1
    int b = tid >> 14;                          // /(DI*DSTATE = 16384)
    int ds = tid & 16383;                       // d*16 + s
    float h = 0.f;
#pragma unroll
    for (int c = 0; c < NCH; c++) {
        size_t o = (((size_t)(b * NCH + c)) << 14) + ds;
        hstart[o] = h;
        h = dchunk[o] * h + hend[o];
    }
}

// ---------------------------------------------------------------- chunked scan, phase 3
// 4 states/lane, seeded with hstart; y + u*Dp + silu(z) gate -> ybf
__global__ __launch_bounds__(256) void k_scan_p3(const float* __restrict__ xdbl,
                                                 const float* __restrict__ dt,
                                                 const float* __restrict__ u,
                                                 const float* __restrict__ xz,
                                                 const float* __restrict__ A_log,
                                                 const float* __restrict__ Dp,
                                                 const float* __restrict__ hstart,
                                                 unsigned short* __restrict__ yout) {
    int bc = blockIdx.x >> 4;
    int d0 = (blockIdx.x & 15) << 6;
    int b = bc >> 5;                   // NCH == 32
    int c = bc & (NCH - 1);
    int tid = threadIdx.x;
    int q = tid & 3, dl = tid >> 2;
    int d = d0 + dl;
    float4 av = *(const float4*)&A_log[((size_t)d << 4) + 4 * q];
    float a0 = -expf(av.x), a1 = -expf(av.y), a2 = -expf(av.z), a3 = -expf(av.w);
    size_t o = ((size_t)bc << 14) + ((size_t)d << 4) + 4 * q;
    float4 hv = *(const float4*)&hstart[o];
    float h0 = hv.x, h1 = hv.y, h2 = hv.z, h3 = hv.w;
    float Dv = Dp[d];
    __shared__ float sdt[32][65], su[32][65], sz[32][65];
    __shared__ __align__(16) float sBC[32][32];
    int tbase = c * CHUNK;
    for (int t0 = 0; t0 < CHUNK; t0 += 32) {
        __syncthreads();
#pragma unroll
        for (int i = 0; i < 8; i++) {
            int e = i * 256 + tid;
            int tt = e >> 6, j = e & 63;
            size_t rowm = (size_t)(b * SQ + tbase + t0 + tt);
            sdt[tt][j] = dt[rowm * DI + d0 + j];
            su[tt][j]  = u[rowm * DI + d0 + j];
            sz[tt][j]  = xz[rowm * (2 * DI) + DI + d0 + j];
        }
#pragma unroll
        for (int i = 0; i < 4; i++) {
            int e = i * 256 + tid;
            int tt = e >> 5, j = e & 31;
            size_t rowm = (size_t)(b * SQ + tbase + t0 + tt);
            sBC[tt][j] = xdbl[rowm * 64 + DTR + j];
        }
        __syncthreads();
        for (int tt = 0; tt < 32; tt++) {
            float dtv = sdt[tt][dl], uv = su[tt][dl];
            float dtu = dtv * uv;
            float4 Bv = *(const float4*)&sBC[tt][4 * q];
            float4 Cv = *(const float4*)&sBC[tt][16 + 4 * q];
            h0 = __expf(dtv * a0) * h0 + dtu * Bv.x;
            h1 = __expf(dtv * a1) * h1 + dtu * Bv.y;
            h2 = __expf(dtv * a2) * h2 + dtu * Bv.z;
            h3 = __expf(dtv * a3) * h3 + dtu * Bv.w;
            float y = h0 * Cv.x + h1 * Cv.y + h2 * Cv.z + h3 * Cv.w;
            y += __shfl_xor(y, 1);
            y += __shfl_xor(y, 2);
            if (q == 0) {
                y += uv * Dv;
                float zv = sz[tt][dl];
                float g = zv / (1.f + __expf(-zv));
                yout[(size_t)(b * SQ + tbase + t0 + tt) * DI + d] = f2bf(y * g);
            }
        }
    }
}

// ---------------------------------------------------------------- emb gather (mask is int32)
__global__ __launch_bounds__(256) void k_emb(const float* __restrict__ tokens,
                                             const int* __restrict__ mask,
                                             float* __restrict__ emb) {
    int b = blockIdx.x;
    int cnt = 0;
    for (int i = threadIdx.x; i < SQ; i += 256) cnt += mask[b * SQ + i] ? 1 : 0;
#pragma unroll
    for (int off = 32; off >= 1; off >>= 1) cnt += __shfl_xor(cnt, off);
    __shared__ int wc[4];
    if ((threadIdx.x & 63) == 0) wc[threadIdx.x >> 6] = cnt;
    __syncthreads();
    int total = wc[0] + wc[1] + wc[2] + wc[3];
    int idx = total > 0 ? total - 1 : 0;
    for (int i = threadIdx.x; i < DM; i += 256)
        emb[b * DM + i] = tokens[((size_t)b * SQ + idx) * DM + i];
}

// ---------------------------------------------------------------- host
extern "C" void kernel_launch(void* const* d_in, const int* in_sizes, int n_in,
                              void* d_out, int out_size, void* d_ws, size_t ws_size,
                              hipStream_t stream) {
    const float* input_data   = (const float*)d_in[0];
    const int*   mask         = (const int*)d_in[1];
    const float* in_proj_w    = (const float*)d_in[2];
    const float* conv_w       = (const float*)d_in[3];
    const float* conv_b       = (const float*)d_in[4];
    const float* xproj_w      = (const float*)d_in[5];
    const float* dtproj_w     = (const float*)d_in[6];
    const float* dtproj_b     = (const float*)d_in[7];
    const float* A_log        = (const float*)d_in[8];
    const float* Dp           = (const float*)d_in[9];
    const float* outproj_w    = (const float*)d_in[10];
    const float* norm_w       = (const float*)d_in[11];
    const float* final_norm_w = (const float*)d_in[12];
    float* out = (float*)d_out;

    const size_t M = (size_t)BQ * SQ;  // 4096
    const size_t CS = (size_t)BQ * NCH * DI * DSTATE;  // 1,048,576
    float* x              = (float*)d_ws;                       // M*DM f32
    unsigned short* xn_bf = (unsigned short*)(x + M * DM);      // M*DM bf16
    float* xz             = (float*)(xn_bf + M * DM);           // M*2DI f32
    float* u              = xz + M * 2 * DI;                    // M*DI f32
    float* xdbl           = u + M * DI;                         // M*64 f32
    float* dtb            = xdbl + M * 64;                      // M*DI f32
    unsigned short* ubf   = (unsigned short*)(dtb + M * DI);    // M*DI bf16
    unsigned short* ybf   = ubf + M * DI;                       // M*DI bf16
    float* hend           = (float*)(ybf + M * DI);             // CS f32
    float* dchunk         = hend + CS;                          // CS f32
    float* hstart         = dchunk + CS;                        // CS f32
    unsigned short* wbf_in  = (unsigned short*)(hstart + CS);   // L*2DI*DM bf16
    unsigned short* wbf_out = wbf_in + (size_t)NLAYERS * 2 * DI * DM;  // L*DM*DI
    unsigned short* wbf_x   = wbf_out + (size_t)NLAYERS * DM * DI;     // L*64*DI

    // weight conversions (per-launch; inputs restored before each timed call)
    {
        int n4 = NLAYERS * 2 * DI * DM / 4;
        k_cvt<<<(n4 + 255) / 256, 256, 0, stream>>>(in_proj_w, wbf_in, n4);
        n4 = NLAYERS * DM * DI / 4;
        k_cvt<<<(n4 + 255) / 256, 256, 0, stream>>>(outproj_w, wbf_out, n4);
        n4 = NLAYERS * 64 * DI / 4;
        k_cvt<<<(n4 + 255) / 256, 256, 0, stream>>>(xproj_w, wbf_x, n4);
    }

    // x = transpose(input_data)
    k_transpose<<<dim3(SQ / 32, DM / 32, BQ), dim3(32, 8), 0, stream>>>(input_data, x);

    for (int l = 0; l < NLAYERS; l++) {
        // xn_bf = bf16(rmsnorm(x))
        k_rmsnorm_bf<<<M, 256, 0, stream>>>(x, norm_w + (size_t)l * DM, xn_bf);
        // xz = xn @ in_proj^T   (M x 2048, K=512)  [MFMA]
        k_gemm_bf16<<<dim3(2 * DI / 128, M / 128), 256, 0, stream>>>(
            xn_bf, DM, wbf_in + (size_t)l * 2 * DI * DM, DM, xz, 2 * DI, DM,
            nullptr, 0);
        // u = silu(conv(xz[:, :DI])), fp32 + bf16
        k_conv_silu<<<M, 256, 0, stream>>>(xz, conv_w + (size_t)l * DI * DCONV,
                                           conv_b + (size_t)l * DI, u, ubf);
        // xdbl = u @ xproj^T   (M x 64, K=1024)  [MFMA, N=64]
        k_gemm_bf16_n64<<<M / 128, 256, 0, stream>>>(
            ubf, DI, wbf_x + (size_t)l * 64 * DI, DI, xdbl, 64, DI);
        // dt = softplus(xdbl[:, :32] @ dtproj^T + b)   (M x 1024, K=32) [fp32]
        k_gemm<<<dim3(DI / 64, M / 64), 256, 0, stream>>>(
            xdbl, 64, dtproj_w + (size_t)l * DI * DTR, DTR, dtb, DI, DTR,
            dtproj_b + (size_t)l * DI, 1, nullptr, 0);
        // chunked scan
        k_scan_p1<<<BQ * NCH * (DI / 64), 256, 0, stream>>>(
            xdbl, dtb, u, A_log + (size_t)l * DI * DSTATE, hend, dchunk);
        k_scan_p2<<<(BQ * DI * DSTATE) / 256, 256, 0, stream>>>(hend, dchunk, hstart);
        k_scan_p3<<<BQ * NCH * (DI / 64), 256, 0, stream>>>(
            xdbl, dtb, u, xz, A_log + (size_t)l * DI * DSTATE, Dp + (size_t)l * DI,
            hstart, ybf);
        // x = x + ybf @ outproj^T   (M x 512, K=1024)  [MFMA + resid]
        k_gemm_bf16<<<dim3(DM / 128, M / 128), 256, 0, stream>>>(
            ybf, DI, wbf_out + (size_t)l * DM * DI, DI, x, DM, DI,
            x, DM);
    }

    // tokens = rmsnorm(x, final_norm_w) -> d_out (fp32)
    k_rmsnorm_f32<<<M, 256, 0, stream>>>(x, final_norm_w, out);
    // emb
    k_emb<<<BQ, 256, 0, stream>>>(out, mask, out + M * DM);
}